// Round 6
// baseline (682.766 us; speedup 1.0000x reference)
//
#include <hip/hip_runtime.h>
#include <hip/hip_bf16.h>
#include <cstdint>
#include <cstddef>

#define EPS_BN 1e-5f
#define LDK 40          // LDS leading-dim stride in ushorts
#define TILE (128 * LDK)

typedef __attribute__((ext_vector_type(8))) __bf16 bf16x8;
typedef __attribute__((ext_vector_type(4))) float f32x4;

__device__ __forceinline__ unsigned short f2b(float f) {
    __hip_bfloat16 h = __float2bfloat16(f);
    return __builtin_bit_cast(unsigned short, h);
}
__device__ __forceinline__ unsigned int pack2(float a, float b) {
    return (unsigned int)f2b(a) | ((unsigned int)f2b(b) << 16);
}
// wait lgkmcnt(0) only (vmcnt=63, expcnt=7 untouched), then raw barrier
__device__ __forceinline__ void lgkm_barrier() {
    __builtin_amdgcn_s_waitcnt(0xC07F);
    __builtin_amdgcn_s_barrier();
}

// ---------------- prep kernels ----------------

__global__ void prep_bn_kernel(const float* __restrict__ g1, const float* __restrict__ b1,
                               const float* __restrict__ m1, const float* __restrict__ v1,
                               const float* __restrict__ g2, const float* __restrict__ b2,
                               const float* __restrict__ m2, const float* __restrict__ v2,
                               const float* __restrict__ g3, const float* __restrict__ b3,
                               const float* __restrict__ m3, const float* __restrict__ v3,
                               float* __restrict__ bias1, float* __restrict__ bias2,
                               float* __restrict__ bias3) {
    int t = blockIdx.x * 256 + threadIdx.x;
    if (t < 256) {
        float inv = g1[t] * rsqrtf(v1[t] + EPS_BN);
        bias1[t] = b1[t] - m1[t] * inv;
    } else if (t < 512) {
        int c = t - 256;
        float inv = g2[c] * rsqrtf(v2[c] + EPS_BN);
        bias2[c] = b2[c] - m2[c] * inv;
    } else if (t < 1536) {
        int c = t - 512;
        float inv = g3[c] * rsqrtf(v3[c] + EPS_BN);
        bias3[c] = b3[c] - m3[c] * inv;
    }
}

__global__ void repack_w1(const float* __restrict__ w1, const float* __restrict__ g1,
                          const float* __restrict__ v1, unsigned short* __restrict__ w1b) {
    int idx = blockIdx.x * 256 + threadIdx.x;  // < 262144
    int co = idx >> 10;
    float inv = g1[co] * rsqrtf(v1[co] + EPS_BN);
    w1b[idx] = f2b(w1[idx] * inv);
}

__global__ void repack_w2(const float* __restrict__ w2, const float* __restrict__ g2,
                          const float* __restrict__ v2, unsigned short* __restrict__ w2r) {
    int idx = blockIdx.x * 256 + threadIdx.x;  // < 589824
    int k9 = idx >> 16;
    int rem = idx & 65535;
    int co = rem >> 8;
    int ci = rem & 255;
    float inv = g2[co] * rsqrtf(v2[co] + EPS_BN);
    w2r[idx] = f2b(w2[(co * 256 + ci) * 9 + k9] * inv);
}

__global__ void repack_w3(const float* __restrict__ w3, const float* __restrict__ g3,
                          const float* __restrict__ v3, unsigned short* __restrict__ w3b) {
    int idx = blockIdx.x * 256 + threadIdx.x;  // < 262144
    int co = idx >> 8;
    float inv = g3[co] * rsqrtf(v3[co] + EPS_BN);
    w3b[idx] = f2b(w3[idx] * inv);
}

// zero only the halo cells of in2p (116 cells/image * 256 ch)
__global__ void halo_zero(unsigned short* __restrict__ in2p) {
    int idx = blockIdx.x * 256 + threadIdx.x;  // 928*256 = 64*116*32
    int cell = idx >> 5, l8 = idx & 31;
    int n = cell / 116, c = cell % 116;
    int h, w;
    if (c < 30)      { h = 0;      w = c; }
    else if (c < 60) { h = 29;     w = c - 30; }
    else if (c < 88) { h = c - 59; w = 0; }
    else             { h = c - 87; w = 29; }
    uint4 z = {0u, 0u, 0u, 0u};
    *reinterpret_cast<uint4*>(in2p + (((size_t)n * 900) + h * 30 + w) * 256 + l8 * 8) = z;
}

// ---------------- transpose: x (N,1024,784) fp32 -> xt (N,784,1024) bf16 ----------------
__global__ __launch_bounds__(256) void transpose_x(const float* __restrict__ x,
                                                   unsigned short* __restrict__ xt) {
    __shared__ float t[64][65];
    const int tid = threadIdx.x;
    const int sp0 = blockIdx.x * 64;
    const int c0 = blockIdx.y * 64;
    const int n = blockIdx.z;
    const float* xn = x + (size_t)n * 1024 * 784;

#pragma unroll
    for (int it = 0; it < 4; ++it) {
        int ci = it * 16 + (tid >> 4);
        int spl = (tid & 15) * 4;
        int sp = sp0 + spl;
        float4 v = {0.f, 0.f, 0.f, 0.f};
        if (sp < 784) v = *reinterpret_cast<const float4*>(xn + (size_t)(c0 + ci) * 784 + sp);
        t[ci][spl + 0] = v.x;
        t[ci][spl + 1] = v.y;
        t[ci][spl + 2] = v.z;
        t[ci][spl + 3] = v.w;
    }
    __syncthreads();

    unsigned short* xtn = xt + (size_t)n * 784 * 1024;
#pragma unroll
    for (int it = 0; it < 2; ++it) {
        int spl = it * 32 + (tid >> 3);
        int sp = sp0 + spl;
        if (sp >= 784) continue;
        int ci8 = (tid & 7) * 8;
        float v0 = t[ci8 + 0][spl], v1 = t[ci8 + 1][spl];
        float v2 = t[ci8 + 2][spl], v3 = t[ci8 + 3][spl];
        float v4 = t[ci8 + 4][spl], v5 = t[ci8 + 5][spl];
        float v6 = t[ci8 + 6][spl], v7 = t[ci8 + 7][spl];
        uint4 o = {pack2(v0, v1), pack2(v2, v3), pack2(v4, v5), pack2(v6, v7)};
        *reinterpret_cast<uint4*>(xtn + (size_t)sp * 1024 + c0 + ci8) = o;
    }
}

// ---------------- MFMA inner step ----------------
// As[m][k] stride LDK (m = A-tile row), Bs[n][k] stride LDK (n = B-tile row).
// D: row(quad*4+reg) follows A, col(lane&15) follows B.
__device__ __forceinline__ void mfma_step(const unsigned short* As, const unsigned short* Bs,
                                          int aoff, int boff, f32x4 acc[4][4]) {
    bf16x8 a[4], b[4];
#pragma unroll
    for (int i = 0; i < 4; ++i)
        a[i] = *reinterpret_cast<const bf16x8*>(As + aoff + i * 16 * LDK);
#pragma unroll
    for (int j = 0; j < 4; ++j)
        b[j] = *reinterpret_cast<const bf16x8*>(Bs + boff + j * 16 * LDK);
#pragma unroll
    for (int i = 0; i < 4; ++i)
#pragma unroll
        for (int j = 0; j < 4; ++j)
            acc[i][j] = __builtin_amdgcn_mfma_f32_16x16x32_bf16(a[i], b[j], acc[i][j], 0, 0, 0);
}

// ---------------- conv1: 1x1 1024->256 GEMM, 2-deep prefetch; out NHWC bf16 + halo --------
// grid (392 flat-sp tiles, 2 co tiles), 256 threads
__global__ __launch_bounds__(256) void conv1_kernel(const unsigned short* __restrict__ xt,
                                                    const unsigned short* __restrict__ w1b,
                                                    const float* __restrict__ bias1,
                                                    unsigned short* __restrict__ in2p) {
    __shared__ unsigned short As[2][TILE];
    __shared__ unsigned short Bs[2][TILE];
    const int tid = threadIdx.x;
    const int f0 = blockIdx.x * 128;
    const int m0 = blockIdx.y * 128;
    const int lane = tid & 63, wave = tid >> 6;
    const int wr = wave >> 1, wc = wave & 1;
    const int l15 = lane & 15, quad = lane >> 4;
    const int tcid = tid & 3, tcl = tid >> 2;

    const unsigned short* aptr = w1b + (size_t)(m0 + tcl) * 1024 + tcid * 8;
    const unsigned short* bptr = xt + (size_t)(f0 + tcl) * 1024 + tcid * 8;

    f32x4 acc[4][4] = {};
    const int aoff = (wr * 64 + l15) * LDK + quad * 8;
    const int boff = (wc * 64 + l15) * LDK + quad * 8;
    const int wo = tcl * LDK + tcid * 8;

    // 2-deep register prefetch: slot0 = even k-steps, slot1 = odd
    uint4 a0s0, a1s0, b0s0, b1s0, a0s1, a1s1, b0s1, b1s1;
    a0s0 = *reinterpret_cast<const uint4*>(aptr);
    a1s0 = *reinterpret_cast<const uint4*>(aptr + 65536);
    b0s0 = *reinterpret_cast<const uint4*>(bptr);
    b1s0 = *reinterpret_cast<const uint4*>(bptr + 65536);
    a0s1 = *reinterpret_cast<const uint4*>(aptr + 32);
    a1s1 = *reinterpret_cast<const uint4*>(aptr + 65536 + 32);
    b0s1 = *reinterpret_cast<const uint4*>(bptr + 32);
    b1s1 = *reinterpret_cast<const uint4*>(bptr + 65536 + 32);

    for (int kk = 0; kk < 32; kk += 2) {
        {   // even step: slot0, LDS buf 0
            unsigned short* A = As[0];
            unsigned short* B = Bs[0];
            *reinterpret_cast<uint4*>(A + wo) = a0s0;
            *reinterpret_cast<uint4*>(A + 64 * LDK + wo) = a1s0;
            *reinterpret_cast<uint4*>(B + wo) = b0s0;
            *reinterpret_cast<uint4*>(B + 64 * LDK + wo) = b1s0;
            if (kk < 30) {
                int k0 = (kk + 2) * 32;
                a0s0 = *reinterpret_cast<const uint4*>(aptr + k0);
                a1s0 = *reinterpret_cast<const uint4*>(aptr + 65536 + k0);
                b0s0 = *reinterpret_cast<const uint4*>(bptr + k0);
                b1s0 = *reinterpret_cast<const uint4*>(bptr + 65536 + k0);
            }
            lgkm_barrier();
            mfma_step(A, B, aoff, boff, acc);
        }
        {   // odd step: slot1, LDS buf 1
            unsigned short* A = As[1];
            unsigned short* B = Bs[1];
            *reinterpret_cast<uint4*>(A + wo) = a0s1;
            *reinterpret_cast<uint4*>(A + 64 * LDK + wo) = a1s1;
            *reinterpret_cast<uint4*>(B + wo) = b0s1;
            *reinterpret_cast<uint4*>(B + 64 * LDK + wo) = b1s1;
            if (kk < 30) {
                int k0 = (kk + 3) * 32;
                a0s1 = *reinterpret_cast<const uint4*>(aptr + k0);
                a1s1 = *reinterpret_cast<const uint4*>(aptr + 65536 + k0);
                b0s1 = *reinterpret_cast<const uint4*>(bptr + k0);
                b1s1 = *reinterpret_cast<const uint4*>(bptr + 65536 + k0);
            }
            lgkm_barrier();
            mfma_step(A, B, aoff, boff, acc);
        }
    }

    // epilogue: bias + relu -> bf16 NHWC with +1 halo offset
#pragma unroll
    for (int j = 0; j < 4; ++j) {
        int f = f0 + wc * 64 + j * 16 + l15;
        int n = f / 784;
        int r = f - n * 784;
        int oh = r / 28, ow = r - oh * 28;
        unsigned short* dst = in2p + ((size_t)n * 900 + (oh + 1) * 30 + (ow + 1)) * 256;
#pragma unroll
        for (int i = 0; i < 4; ++i) {
            int co = m0 + wr * 64 + i * 16 + quad * 4;
            float4 bia = *reinterpret_cast<const float4*>(bias1 + co);
            f32x4 v = acc[i][j];
            ushort4 o;
            o.x = f2b(fmaxf(v.x + bia.x, 0.f));
            o.y = f2b(fmaxf(v.y + bia.y, 0.f));
            o.z = f2b(fmaxf(v.z + bia.z, 0.f));
            o.w = f2b(fmaxf(v.w + bia.w, 0.f));
            *reinterpret_cast<ushort4*>(dst + co) = o;
        }
    }
}

// ---------------- conv2: 3x3 = 72 k-steps, 2-deep prefetch; out flat [f][256] bf16 --------
// grid (392, 2), 256 threads
__global__ __launch_bounds__(256) void conv2_kernel(const unsigned short* __restrict__ in2p,
                                                    const unsigned short* __restrict__ w2r,
                                                    const float* __restrict__ bias2,
                                                    unsigned short* __restrict__ in3) {
    __shared__ unsigned short As[2][TILE];
    __shared__ unsigned short Bs[2][TILE];
    const int tid = threadIdx.x;
    const int f0 = blockIdx.x * 128;
    const int m0 = blockIdx.y * 128;
    const int lane = tid & 63, wave = tid >> 6;
    const int wr = wave >> 1, wc = wave & 1;
    const int l15 = lane & 15, quad = lane >> 4;
    const int tcid = tid & 3, tcl = tid >> 2;

    // per-thread halo-center cell index for its two B rows
    int cellc[2];
#pragma unroll
    for (int p = 0; p < 2; ++p) {
        int f = f0 + p * 64 + tcl;
        int n = f / 784;
        int r = f - n * 784;
        int oh = r / 28, ow = r - oh * 28;
        cellc[p] = n * 900 + (oh + 1) * 30 + (ow + 1);
    }

    f32x4 acc[4][4] = {};
    const int aoff = (wr * 64 + l15) * LDK + quad * 8;
    const int boff = (wc * 64 + l15) * LDK + quad * 8;
    const int wo = tcl * LDK + tcid * 8;

    uint4 a0s0, a1s0, b0s0, b1s0, a0s1, a1s1, b0s1, b1s1;
    {   // kn=0: k9=0, cb=0, dd=-31
        a0s0 = *reinterpret_cast<const uint4*>(w2r + (size_t)(m0 + tcl) * 256 + tcid * 8);
        a1s0 = *reinterpret_cast<const uint4*>(w2r + (size_t)(m0 + 64 + tcl) * 256 + tcid * 8);
        b0s0 = *reinterpret_cast<const uint4*>(in2p + (size_t)(cellc[0] - 31) * 256 + tcid * 8);
        b1s0 = *reinterpret_cast<const uint4*>(in2p + (size_t)(cellc[1] - 31) * 256 + tcid * 8);
    }
    {   // kn=1: k9=0, cb=1, dd=-31
        const unsigned short* wb = w2r + 32;
        a0s1 = *reinterpret_cast<const uint4*>(wb + (size_t)(m0 + tcl) * 256 + tcid * 8);
        a1s1 = *reinterpret_cast<const uint4*>(wb + (size_t)(m0 + 64 + tcl) * 256 + tcid * 8);
        const unsigned short* bb = in2p + 32 + tcid * 8;
        b0s1 = *reinterpret_cast<const uint4*>(bb + (size_t)(cellc[0] - 31) * 256);
        b1s1 = *reinterpret_cast<const uint4*>(bb + (size_t)(cellc[1] - 31) * 256);
    }

    for (int kk = 0; kk < 72; kk += 2) {
        {   // even step: slot0, LDS buf 0
            unsigned short* A = As[0];
            unsigned short* B = Bs[0];
            *reinterpret_cast<uint4*>(A + wo) = a0s0;
            *reinterpret_cast<uint4*>(A + 64 * LDK + wo) = a1s0;
            *reinterpret_cast<uint4*>(B + wo) = b0s0;
            *reinterpret_cast<uint4*>(B + 64 * LDK + wo) = b1s0;
            if (kk < 70) {
                int kn = kk + 2;
                int k9 = kn >> 3, cb = kn & 7;
                int kh = k9 / 3, kw = k9 - 3 * kh;
                int dd = (kh - 1) * 30 + (kw - 1);
                const unsigned short* wb = w2r + (size_t)k9 * 65536 + cb * 32;
                a0s0 = *reinterpret_cast<const uint4*>(wb + (size_t)(m0 + tcl) * 256 + tcid * 8);
                a1s0 = *reinterpret_cast<const uint4*>(wb + (size_t)(m0 + 64 + tcl) * 256 + tcid * 8);
                const unsigned short* bb = in2p + (size_t)cb * 32 + tcid * 8;
                b0s0 = *reinterpret_cast<const uint4*>(bb + (size_t)(cellc[0] + dd) * 256);
                b1s0 = *reinterpret_cast<const uint4*>(bb + (size_t)(cellc[1] + dd) * 256);
            }
            lgkm_barrier();
            mfma_step(A, B, aoff, boff, acc);
        }
        {   // odd step: slot1, LDS buf 1
            unsigned short* A = As[1];
            unsigned short* B = Bs[1];
            *reinterpret_cast<uint4*>(A + wo) = a0s1;
            *reinterpret_cast<uint4*>(A + 64 * LDK + wo) = a1s1;
            *reinterpret_cast<uint4*>(B + wo) = b0s1;
            *reinterpret_cast<uint4*>(B + 64 * LDK + wo) = b1s1;
            if (kk < 70) {
                int kn = kk + 3;
                int k9 = kn >> 3, cb = kn & 7;
                int kh = k9 / 3, kw = k9 - 3 * kh;
                int dd = (kh - 1) * 30 + (kw - 1);
                const unsigned short* wb = w2r + (size_t)k9 * 65536 + cb * 32;
                a0s1 = *reinterpret_cast<const uint4*>(wb + (size_t)(m0 + tcl) * 256 + tcid * 8);
                a1s1 = *reinterpret_cast<const uint4*>(wb + (size_t)(m0 + 64 + tcl) * 256 + tcid * 8);
                const unsigned short* bb = in2p + (size_t)cb * 32 + tcid * 8;
                b0s1 = *reinterpret_cast<const uint4*>(bb + (size_t)(cellc[0] + dd) * 256);
                b1s1 = *reinterpret_cast<const uint4*>(bb + (size_t)(cellc[1] + dd) * 256);
            }
            lgkm_barrier();
            mfma_step(A, B, aoff, boff, acc);
        }
    }

    // epilogue: bias + relu -> bf16, flat [f][256]
#pragma unroll
    for (int j = 0; j < 4; ++j) {
        int f = f0 + wc * 64 + j * 16 + l15;
        unsigned short* dst = in3 + (size_t)f * 256;
#pragma unroll
        for (int i = 0; i < 4; ++i) {
            int co = m0 + wr * 64 + i * 16 + quad * 4;
            float4 bia = *reinterpret_cast<const float4*>(bias2 + co);
            f32x4 v = acc[i][j];
            ushort4 o;
            o.x = f2b(fmaxf(v.x + bia.x, 0.f));
            o.y = f2b(fmaxf(v.y + bia.y, 0.f));
            o.z = f2b(fmaxf(v.z + bia.z, 0.f));
            o.w = f2b(fmaxf(v.w + bia.w, 0.f));
            *reinterpret_cast<ushort4*>(dst + co) = o;
        }
    }
}

// ---------------- conv3: 1x1 256->1024, LDS-FREE direct GEMM; BN+res+ReLU fp32 ------------
// K=256 and both operands are cache-resident (in3 25.7MB -> L3, w3b 512KB -> L2), so each
// lane loads its MFMA fragments straight from global: row = base+l15, bytes quad*16+kk*64
// -> every 64B line fully consumed by 4 lanes (perfect coalescing). NO LDS, NO barriers:
// waves free-run, the R5-diagnosed barrier-drain stall disappears. Residual x folded into
// acc-init (C-in). grid (8 co-tiles, 392 f-tiles) so consecutive blocks share the in3
// f-panel via L2. 256 threads.
__global__ __launch_bounds__(256) void conv3_kernel(const unsigned short* __restrict__ in3,
                                                    const unsigned short* __restrict__ w3b,
                                                    const float* __restrict__ bias3,
                                                    const float* __restrict__ x,
                                                    float* __restrict__ out) {
    const int tid = threadIdx.x;
    const int m0 = blockIdx.x * 128;   // co tile (fast dim: 8 blocks share f-panel)
    const int f0 = blockIdx.y * 128;   // flat-spatial tile
    const int lane = tid & 63, wave = tid >> 6;
    const int wr = wave >> 1, wc = wave & 1;
    const int l15 = lane & 15, quad = lane >> 4;

    // fragment base pointers (A rows = f, B rows = co; 8 bf16 at k-offset quad*8)
    const unsigned short* abase = in3 + (size_t)(f0 + wr * 64 + l15) * 256 + quad * 8;
    const unsigned short* bbase = w3b + (size_t)(m0 + wc * 64 + l15) * 256 + quad * 8;

    // accumulator init = residual + bias (HBM x-read overlaps the k-loop via C-in)
    f32x4 acc[4][4];
#pragma unroll
    for (int j = 0; j < 4; ++j) {
        int co = m0 + wc * 64 + j * 16 + l15;
        float b = bias3[co];
#pragma unroll
        for (int i = 0; i < 4; ++i) {
            int fb = f0 + wr * 64 + i * 16 + quad * 4;
            int n = fb / 784;
            int sp = fb - n * 784;
            float4 xr = *reinterpret_cast<const float4*>(x + ((size_t)n * 1024 + co) * 784 + sp);
            f32x4 a;
            a.x = xr.x + b;
            a.y = xr.y + b;
            a.z = xr.z + b;
            a.w = xr.w + b;
            acc[i][j] = a;
        }
    }

    // K loop: 8 steps of 16x16x32, fragments direct from L2/L3, fully unrolled, no sync
#pragma unroll
    for (int kk = 0; kk < 8; ++kk) {
        bf16x8 a[4], b[4];
#pragma unroll
        for (int i = 0; i < 4; ++i)
            a[i] = *reinterpret_cast<const bf16x8*>(abase + i * 16 * 256 + kk * 32);
#pragma unroll
        for (int j = 0; j < 4; ++j)
            b[j] = *reinterpret_cast<const bf16x8*>(bbase + j * 16 * 256 + kk * 32);
#pragma unroll
        for (int i = 0; i < 4; ++i)
#pragma unroll
            for (int j = 0; j < 4; ++j)
                acc[i][j] = __builtin_amdgcn_mfma_f32_16x16x32_bf16(a[i], b[j], acc[i][j], 0, 0, 0);
    }

    // epilogue: pure relu + float4 store (residual+bias already inside acc)
#pragma unroll
    for (int j = 0; j < 4; ++j) {
        int co = m0 + wc * 64 + j * 16 + l15;
#pragma unroll
        for (int i = 0; i < 4; ++i) {
            int fb = f0 + wr * 64 + i * 16 + quad * 4;
            int n = fb / 784;
            int sp = fb - n * 784;
            size_t off = ((size_t)n * 1024 + co) * 784 + sp;
            f32x4 v = acc[i][j];
            float4 o;
            o.x = fmaxf(v.x, 0.f);
            o.y = fmaxf(v.y, 0.f);
            o.z = fmaxf(v.z, 0.f);
            o.w = fmaxf(v.w, 0.f);
            *reinterpret_cast<float4*>(out + off) = o;
        }
    }
}

// ---------------- launch ----------------

extern "C" void kernel_launch(void* const* d_in, const int* in_sizes, int n_in,
                              void* d_out, int out_size, void* d_ws, size_t ws_size,
                              hipStream_t stream) {
    const float* x  = (const float*)d_in[0];
    const float* w1 = (const float*)d_in[1];
    const float* w2 = (const float*)d_in[2];
    const float* w3 = (const float*)d_in[3];
    const float* g1 = (const float*)d_in[4];
    const float* b1 = (const float*)d_in[5];
    const float* m1 = (const float*)d_in[6];
    const float* v1 = (const float*)d_in[7];
    const float* g2 = (const float*)d_in[8];
    const float* b2 = (const float*)d_in[9];
    const float* m2 = (const float*)d_in[10];
    const float* v2 = (const float*)d_in[11];
    const float* g3 = (const float*)d_in[12];
    const float* b3 = (const float*)d_in[13];
    const float* m3 = (const float*)d_in[14];
    const float* v3 = (const float*)d_in[15];

    char* ws = (char*)d_ws;
    unsigned short* w1b  = (unsigned short*)(ws + 0);         //   524288 B
    unsigned short* w2r  = (unsigned short*)(ws + 524288);    //  1179648 B
    unsigned short* w3b  = (unsigned short*)(ws + 1703936);   //   524288 B
    float* bias1         = (float*)(ws + 2228224);            //     1024 B
    float* bias2         = (float*)(ws + 2229248);            //     1024 B
    float* bias3         = (float*)(ws + 2230272);            //     4096 B
    unsigned short* in2p = (unsigned short*)(ws + 2234368);   // 29491200 B (64*900*256 bf16)
    unsigned short* xt   = (unsigned short*)(ws + 31725568);  // 102760448 B (64*784*1024 bf16)
    unsigned short* in3  = xt;  // aliases xt: xt is dead once conv1 finishes
    // total: 134486016 B (~134.5 MB)

    prep_bn_kernel<<<6, 256, 0, stream>>>(g1, b1, m1, v1, g2, b2, m2, v2, g3, b3, m3, v3,
                                          bias1, bias2, bias3);
    repack_w1<<<1024, 256, 0, stream>>>(w1, g1, v1, w1b);
    repack_w2<<<2304, 256, 0, stream>>>(w2, g2, v2, w2r);
    repack_w3<<<1024, 256, 0, stream>>>(w3, g3, v3, w3b);
    halo_zero<<<928, 256, 0, stream>>>(in2p);

    transpose_x<<<dim3(13, 16, 64), 256, 0, stream>>>(x, xt);
    conv1_kernel<<<dim3(392, 2), 256, 0, stream>>>(xt, w1b, bias1, in2p);
    conv2_kernel<<<dim3(392, 2), 256, 0, stream>>>(in2p, w2r, bias2, in3);
    conv3_kernel<<<dim3(8, 392), 256, 0, stream>>>(in3, w3b, bias3, x, (float*)d_out);
}

// Round 7
// 680.332 us; speedup vs baseline: 1.0036x; 1.0036x over previous
//
#include <hip/hip_runtime.h>
#include <hip/hip_bf16.h>
#include <cstdint>
#include <cstddef>

#define EPS_BN 1e-5f
#define LDK 32          // LDS leading-dim stride in ushorts (linear: global_load_lds needs it)
#define TILE (128 * LDK)

typedef __attribute__((ext_vector_type(8))) __bf16 bf16x8;
typedef __attribute__((ext_vector_type(4))) float f32x4;

__device__ __forceinline__ unsigned short f2b(float f) {
    __hip_bfloat16 h = __float2bfloat16(f);
    return __builtin_bit_cast(unsigned short, h);
}
__device__ __forceinline__ unsigned int pack2(float a, float b) {
    return (unsigned int)f2b(a) | ((unsigned int)f2b(b) << 16);
}
// wait vmcnt(0) only (lgkmcnt=63, expcnt=7 untouched), then raw barrier.
// Used after global_load_lds staging: DMA completion is tracked by vmcnt.
__device__ __forceinline__ void vm_barrier() {
    __builtin_amdgcn_s_waitcnt(0x3F70);
    __builtin_amdgcn_s_barrier();
}
// async global->LDS DMA, 16B per lane: writes lds_base + lane*16
__device__ __forceinline__ void load_lds16(const unsigned short* g, unsigned short* l) {
    __builtin_amdgcn_global_load_lds(
        (__attribute__((address_space(1))) void*)g,
        (__attribute__((address_space(3))) void*)l, 16, 0, 0);
}

// ---------------- prep kernels ----------------

__global__ void prep_bn_kernel(const float* __restrict__ g1, const float* __restrict__ b1,
                               const float* __restrict__ m1, const float* __restrict__ v1,
                               const float* __restrict__ g2, const float* __restrict__ b2,
                               const float* __restrict__ m2, const float* __restrict__ v2,
                               const float* __restrict__ g3, const float* __restrict__ b3,
                               const float* __restrict__ m3, const float* __restrict__ v3,
                               float* __restrict__ bias1, float* __restrict__ bias2,
                               float* __restrict__ bias3) {
    int t = blockIdx.x * 256 + threadIdx.x;
    if (t < 256) {
        float inv = g1[t] * rsqrtf(v1[t] + EPS_BN);
        bias1[t] = b1[t] - m1[t] * inv;
    } else if (t < 512) {
        int c = t - 256;
        float inv = g2[c] * rsqrtf(v2[c] + EPS_BN);
        bias2[c] = b2[c] - m2[c] * inv;
    } else if (t < 1536) {
        int c = t - 512;
        float inv = g3[c] * rsqrtf(v3[c] + EPS_BN);
        bias3[c] = b3[c] - m3[c] * inv;
    }
}

__global__ void repack_w1(const float* __restrict__ w1, const float* __restrict__ g1,
                          const float* __restrict__ v1, unsigned short* __restrict__ w1b) {
    int idx = blockIdx.x * 256 + threadIdx.x;  // < 262144
    int co = idx >> 10;
    float inv = g1[co] * rsqrtf(v1[co] + EPS_BN);
    w1b[idx] = f2b(w1[idx] * inv);
}

__global__ void repack_w2(const float* __restrict__ w2, const float* __restrict__ g2,
                          const float* __restrict__ v2, unsigned short* __restrict__ w2r) {
    int idx = blockIdx.x * 256 + threadIdx.x;  // < 589824
    int k9 = idx >> 16;
    int rem = idx & 65535;
    int co = rem >> 8;
    int ci = rem & 255;
    float inv = g2[co] * rsqrtf(v2[co] + EPS_BN);
    w2r[idx] = f2b(w2[(co * 256 + ci) * 9 + k9] * inv);
}

__global__ void repack_w3(const float* __restrict__ w3, const float* __restrict__ g3,
                          const float* __restrict__ v3, unsigned short* __restrict__ w3b) {
    int idx = blockIdx.x * 256 + threadIdx.x;  // < 262144
    int co = idx >> 8;
    float inv = g3[co] * rsqrtf(v3[co] + EPS_BN);
    w3b[idx] = f2b(w3[idx] * inv);
}

// zero only the halo cells of in2p (116 cells/image * 256 ch)
__global__ void halo_zero(unsigned short* __restrict__ in2p) {
    int idx = blockIdx.x * 256 + threadIdx.x;  // 928*256 = 64*116*32
    int cell = idx >> 5, l8 = idx & 31;
    int n = cell / 116, c = cell % 116;
    int h, w;
    if (c < 30)      { h = 0;      w = c; }
    else if (c < 60) { h = 29;     w = c - 30; }
    else if (c < 88) { h = c - 59; w = 0; }
    else             { h = c - 87; w = 29; }
    uint4 z = {0u, 0u, 0u, 0u};
    *reinterpret_cast<uint4*>(in2p + (((size_t)n * 900) + h * 30 + w) * 256 + l8 * 8) = z;
}

// ---------------- transpose: x (N,1024,784) fp32 -> xt (N,784,1024) bf16 ----------------
__global__ __launch_bounds__(256) void transpose_x(const float* __restrict__ x,
                                                   unsigned short* __restrict__ xt) {
    __shared__ float t[64][65];
    const int tid = threadIdx.x;
    const int sp0 = blockIdx.x * 64;
    const int c0 = blockIdx.y * 64;
    const int n = blockIdx.z;
    const float* xn = x + (size_t)n * 1024 * 784;

#pragma unroll
    for (int it = 0; it < 4; ++it) {
        int ci = it * 16 + (tid >> 4);
        int spl = (tid & 15) * 4;
        int sp = sp0 + spl;
        float4 v = {0.f, 0.f, 0.f, 0.f};
        if (sp < 784) v = *reinterpret_cast<const float4*>(xn + (size_t)(c0 + ci) * 784 + sp);
        t[ci][spl + 0] = v.x;
        t[ci][spl + 1] = v.y;
        t[ci][spl + 2] = v.z;
        t[ci][spl + 3] = v.w;
    }
    __syncthreads();

    unsigned short* xtn = xt + (size_t)n * 784 * 1024;
#pragma unroll
    for (int it = 0; it < 2; ++it) {
        int spl = it * 32 + (tid >> 3);
        int sp = sp0 + spl;
        if (sp >= 784) continue;
        int ci8 = (tid & 7) * 8;
        float v0 = t[ci8 + 0][spl], v1 = t[ci8 + 1][spl];
        float v2 = t[ci8 + 2][spl], v3 = t[ci8 + 3][spl];
        float v4 = t[ci8 + 4][spl], v5 = t[ci8 + 5][spl];
        float v6 = t[ci8 + 6][spl], v7 = t[ci8 + 7][spl];
        uint4 o = {pack2(v0, v1), pack2(v2, v3), pack2(v4, v5), pack2(v6, v7)};
        *reinterpret_cast<uint4*>(xtn + (size_t)sp * 1024 + c0 + ci8) = o;
    }
}

// ---------------- MFMA inner step ----------------
// As[m][k] stride LDK (m = A-tile row), Bs[n][k] stride LDK (n = B-tile row).
// D: row(quad*4+reg) follows A, col(lane&15) follows B.
__device__ __forceinline__ void mfma_step(const unsigned short* As, const unsigned short* Bs,
                                          int aoff, int boff, f32x4 acc[4][4]) {
    bf16x8 a[4], b[4];
#pragma unroll
    for (int i = 0; i < 4; ++i)
        a[i] = *reinterpret_cast<const bf16x8*>(As + aoff + i * 16 * LDK);
#pragma unroll
    for (int j = 0; j < 4; ++j)
        b[j] = *reinterpret_cast<const bf16x8*>(Bs + boff + j * 16 * LDK);
#pragma unroll
    for (int i = 0; i < 4; ++i)
#pragma unroll
        for (int j = 0; j < 4; ++j)
            acc[i][j] = __builtin_amdgcn_mfma_f32_16x16x32_bf16(a[i], b[j], acc[i][j], 0, 0, 0);
}

// Staging via global_load_lds: wave w stages rows [16w,16w+16) (+64 for second half);
// lane l -> row 16w + l/4, col (l&3)*16B. LDS dest = per-wave base + lane*16 (linear).

// ---------------- conv1: 1x1 1024->256 GEMM, DMA-staged; out NHWC bf16 + halo -------------
// grid (392 flat-sp tiles, 2 co tiles), 256 threads
__global__ __launch_bounds__(256) void conv1_kernel(const unsigned short* __restrict__ xt,
                                                    const unsigned short* __restrict__ w1b,
                                                    const float* __restrict__ bias1,
                                                    unsigned short* __restrict__ in2p) {
    __shared__ unsigned short As[2][TILE];
    __shared__ unsigned short Bs[2][TILE];
    const int tid = threadIdx.x;
    const int f0 = blockIdx.x * 128;
    const int m0 = blockIdx.y * 128;
    const int lane = tid & 63, wave = tid >> 6;
    const int wr = wave >> 1, wc = wave & 1;
    const int l15 = lane & 15, quad = lane >> 4;
    const int srow = wave * 16 + (lane >> 2);
    const int scol8 = (lane & 3) * 8;
    const int lso = wave * 512;  // per-wave LDS ushort base (16 rows * 32)

    const unsigned short* ga = w1b + (size_t)(m0 + srow) * 1024 + scol8;
    const unsigned short* gb = xt + (size_t)(f0 + srow) * 1024 + scol8;

    f32x4 acc[4][4] = {};
    const int aoff = (wr * 64 + l15) * LDK + quad * 8;
    const int boff = (wc * 64 + l15) * LDK + quad * 8;

#define STAGE1(cur, k0) do { \
        load_lds16(ga + (k0), &As[cur][lso]); \
        load_lds16(ga + 65536 + (k0), &As[cur][lso + 2048]); \
        load_lds16(gb + (k0), &Bs[cur][lso]); \
        load_lds16(gb + 65536 + (k0), &Bs[cur][lso + 2048]); \
    } while (0)

    STAGE1(0, 0);
    vm_barrier();
    for (int kk = 0; kk < 32; ++kk) {
        if (kk < 31) STAGE1((kk + 1) & 1, (kk + 1) * 32);
        mfma_step(As[kk & 1], Bs[kk & 1], aoff, boff, acc);
        vm_barrier();
    }
#undef STAGE1

    // epilogue: bias + relu -> bf16 NHWC with +1 halo offset
#pragma unroll
    for (int j = 0; j < 4; ++j) {
        int f = f0 + wc * 64 + j * 16 + l15;
        int n = f / 784;
        int r = f - n * 784;
        int oh = r / 28, ow = r - oh * 28;
        unsigned short* dst = in2p + ((size_t)n * 900 + (oh + 1) * 30 + (ow + 1)) * 256;
#pragma unroll
        for (int i = 0; i < 4; ++i) {
            int co = m0 + wr * 64 + i * 16 + quad * 4;
            float4 bia = *reinterpret_cast<const float4*>(bias1 + co);
            f32x4 v = acc[i][j];
            ushort4 o;
            o.x = f2b(fmaxf(v.x + bia.x, 0.f));
            o.y = f2b(fmaxf(v.y + bia.y, 0.f));
            o.z = f2b(fmaxf(v.z + bia.z, 0.f));
            o.w = f2b(fmaxf(v.w + bia.w, 0.f));
            *reinterpret_cast<ushort4*>(dst + co) = o;
        }
    }
}

// ---------------- conv2: 3x3 = 72 k-steps, DMA-staged; out flat [f][256] bf16 -------------
// grid (392, 2), 256 threads
__global__ __launch_bounds__(256) void conv2_kernel(const unsigned short* __restrict__ in2p,
                                                    const unsigned short* __restrict__ w2r,
                                                    const float* __restrict__ bias2,
                                                    unsigned short* __restrict__ in3) {
    __shared__ unsigned short As[2][TILE];
    __shared__ unsigned short Bs[2][TILE];
    const int tid = threadIdx.x;
    const int f0 = blockIdx.x * 128;
    const int m0 = blockIdx.y * 128;
    const int lane = tid & 63, wave = tid >> 6;
    const int wr = wave >> 1, wc = wave & 1;
    const int l15 = lane & 15, quad = lane >> 4;
    const int srow = wave * 16 + (lane >> 2);
    const int scol8 = (lane & 3) * 8;
    const int lso = wave * 512;

    // halo-center cell index for this thread's two staged B rows
    int cellr[2];
#pragma unroll
    for (int p = 0; p < 2; ++p) {
        int f = f0 + p * 64 + srow;
        int n = f / 784;
        int r = f - n * 784;
        int oh = r / 28, ow = r - oh * 28;
        cellr[p] = n * 900 + (oh + 1) * 30 + (ow + 1);
    }

    const unsigned short* wbase = w2r + (size_t)(m0 + srow) * 256 + scol8;

    f32x4 acc[4][4] = {};
    const int aoff = (wr * 64 + l15) * LDK + quad * 8;
    const int boff = (wc * 64 + l15) * LDK + quad * 8;

#define STAGE2(cur, kn) do { \
        int k9_ = (kn) >> 3, cb_ = (kn) & 7; \
        int kh_ = k9_ / 3, kw_ = k9_ - 3 * kh_; \
        int dd_ = (kh_ - 1) * 30 + (kw_ - 1); \
        const unsigned short* wa_ = wbase + (size_t)k9_ * 65536 + cb_ * 32; \
        load_lds16(wa_, &As[cur][lso]); \
        load_lds16(wa_ + 16384, &As[cur][lso + 2048]); \
        const unsigned short* bb_ = in2p + (size_t)cb_ * 32 + scol8; \
        load_lds16(bb_ + (size_t)(cellr[0] + dd_) * 256, &Bs[cur][lso]); \
        load_lds16(bb_ + (size_t)(cellr[1] + dd_) * 256, &Bs[cur][lso + 2048]); \
    } while (0)

    STAGE2(0, 0);
    vm_barrier();
    for (int kk = 0; kk < 72; ++kk) {
        if (kk < 71) STAGE2((kk + 1) & 1, kk + 1);
        mfma_step(As[kk & 1], Bs[kk & 1], aoff, boff, acc);
        vm_barrier();
    }
#undef STAGE2

    // epilogue: bias + relu -> bf16, flat [f][256]
#pragma unroll
    for (int j = 0; j < 4; ++j) {
        int f = f0 + wc * 64 + j * 16 + l15;
        unsigned short* dst = in3 + (size_t)f * 256;
#pragma unroll
        for (int i = 0; i < 4; ++i) {
            int co = m0 + wr * 64 + i * 16 + quad * 4;
            float4 bia = *reinterpret_cast<const float4*>(bias2 + co);
            f32x4 v = acc[i][j];
            ushort4 o;
            o.x = f2b(fmaxf(v.x + bia.x, 0.f));
            o.y = f2b(fmaxf(v.y + bia.y, 0.f));
            o.z = f2b(fmaxf(v.z + bia.z, 0.f));
            o.w = f2b(fmaxf(v.w + bia.w, 0.f));
            *reinterpret_cast<ushort4*>(dst + co) = o;
        }
    }
}

// ---------------- conv3: 1x1 256->1024, DMA-staged; residual in acc-init; fp32 out --------
// A = spatial (in3 rows -> D rows = f), B = weights (w3b rows -> D cols = co).
// R5 structure (LDS + acc-fold, 125us) with reg-staging replaced by global_load_lds.
// grid (392, 8), 256 threads
__global__ __launch_bounds__(256) void conv3_kernel(const unsigned short* __restrict__ in3,
                                                    const unsigned short* __restrict__ w3b,
                                                    const float* __restrict__ bias3,
                                                    const float* __restrict__ x,
                                                    float* __restrict__ out) {
    __shared__ unsigned short As[2][TILE];
    __shared__ unsigned short Bs[2][TILE];
    const int tid = threadIdx.x;
    const int f0 = blockIdx.x * 128;
    const int m0 = blockIdx.y * 128;
    const int lane = tid & 63, wave = tid >> 6;
    const int wr = wave >> 1, wc = wave & 1;
    const int l15 = lane & 15, quad = lane >> 4;
    const int srow = wave * 16 + (lane >> 2);
    const int scol8 = (lane & 3) * 8;
    const int lso = wave * 512;

    const unsigned short* ga = in3 + (size_t)(f0 + srow) * 256 + scol8;   // spatial -> As
    const unsigned short* gb = w3b + (size_t)(m0 + srow) * 256 + scol8;   // weights -> Bs

    const int aoff = (wr * 64 + l15) * LDK + quad * 8;
    const int boff = (wc * 64 + l15) * LDK + quad * 8;

#define STAGE3(cur, k0) do { \
        load_lds16(ga + (k0), &As[cur][lso]); \
        load_lds16(ga + 16384 + (k0), &As[cur][lso + 2048]); \
        load_lds16(gb + (k0), &Bs[cur][lso]); \
        load_lds16(gb + 16384 + (k0), &Bs[cur][lso + 2048]); \
    } while (0)

    STAGE3(0, 0);  // issue first-tile DMA before the x-loads so both streams overlap

    // accumulator init = residual + bias (MFMA C-in carries it through the k-loop)
    f32x4 acc[4][4];
#pragma unroll
    for (int j = 0; j < 4; ++j) {
        int co = m0 + wc * 64 + j * 16 + l15;
        float b = bias3[co];
#pragma unroll
        for (int i = 0; i < 4; ++i) {
            int fb = f0 + wr * 64 + i * 16 + quad * 4;
            int n = fb / 784;
            int sp = fb - n * 784;
            float4 xr = *reinterpret_cast<const float4*>(x + ((size_t)n * 1024 + co) * 784 + sp);
            f32x4 a;
            a.x = xr.x + b;
            a.y = xr.y + b;
            a.z = xr.z + b;
            a.w = xr.w + b;
            acc[i][j] = a;
        }
    }

    vm_barrier();
    for (int kk = 0; kk < 8; ++kk) {
        if (kk < 7) STAGE3((kk + 1) & 1, (kk + 1) * 32);
        mfma_step(As[kk & 1], Bs[kk & 1], aoff, boff, acc);
        vm_barrier();
    }
#undef STAGE3

    // epilogue: pure relu + float4 store (residual+bias already inside acc)
#pragma unroll
    for (int j = 0; j < 4; ++j) {
        int co = m0 + wc * 64 + j * 16 + l15;
#pragma unroll
        for (int i = 0; i < 4; ++i) {
            int fb = f0 + wr * 64 + i * 16 + quad * 4;
            int n = fb / 784;
            int sp = fb - n * 784;
            size_t off = ((size_t)n * 1024 + co) * 784 + sp;
            f32x4 v = acc[i][j];
            float4 o;
            o.x = fmaxf(v.x, 0.f);
            o.y = fmaxf(v.y, 0.f);
            o.z = fmaxf(v.z, 0.f);
            o.w = fmaxf(v.w, 0.f);
            *reinterpret_cast<float4*>(out + off) = o;
        }
    }
}

// ---------------- launch ----------------

extern "C" void kernel_launch(void* const* d_in, const int* in_sizes, int n_in,
                              void* d_out, int out_size, void* d_ws, size_t ws_size,
                              hipStream_t stream) {
    const float* x  = (const float*)d_in[0];
    const float* w1 = (const float*)d_in[1];
    const float* w2 = (const float*)d_in[2];
    const float* w3 = (const float*)d_in[3];
    const float* g1 = (const float*)d_in[4];
    const float* b1 = (const float*)d_in[5];
    const float* m1 = (const float*)d_in[6];
    const float* v1 = (const float*)d_in[7];
    const float* g2 = (const float*)d_in[8];
    const float* b2 = (const float*)d_in[9];
    const float* m2 = (const float*)d_in[10];
    const float* v2 = (const float*)d_in[11];
    const float* g3 = (const float*)d_in[12];
    const float* b3 = (const float*)d_in[13];
    const float* m3 = (const float*)d_in[14];
    const float* v3 = (const float*)d_in[15];

    char* ws = (char*)d_ws;
    unsigned short* w1b  = (unsigned short*)(ws + 0);         //   524288 B
    unsigned short* w2r  = (unsigned short*)(ws + 524288);    //  1179648 B
    unsigned short* w3b  = (unsigned short*)(ws + 1703936);   //   524288 B
    float* bias1         = (float*)(ws + 2228224);            //     1024 B
    float* bias2         = (float*)(ws + 2229248);            //     1024 B
    float* bias3         = (float*)(ws + 2230272);            //     4096 B
    unsigned short* in2p = (unsigned short*)(ws + 2234368);   // 29491200 B (64*900*256 bf16)
    unsigned short* xt   = (unsigned short*)(ws + 31725568);  // 102760448 B (64*784*1024 bf16)
    unsigned short* in3  = xt;  // aliases xt: xt is dead once conv1 finishes
    // total: 134486016 B (~134.5 MB)

    prep_bn_kernel<<<6, 256, 0, stream>>>(g1, b1, m1, v1, g2, b2, m2, v2, g3, b3, m3, v3,
                                          bias1, bias2, bias3);
    repack_w1<<<1024, 256, 0, stream>>>(w1, g1, v1, w1b);
    repack_w2<<<2304, 256, 0, stream>>>(w2, g2, v2, w2r);
    repack_w3<<<1024, 256, 0, stream>>>(w3, g3, v3, w3b);
    halo_zero<<<928, 256, 0, stream>>>(in2p);

    transpose_x<<<dim3(13, 16, 64), 256, 0, stream>>>(x, xt);
    conv1_kernel<<<dim3(392, 2), 256, 0, stream>>>(xt, w1b, bias1, in2p);
    conv2_kernel<<<dim3(392, 2), 256, 0, stream>>>(in2p, w2r, bias2, in3);
    conv3_kernel<<<dim3(392, 8), 256, 0, stream>>>(in3, w3b, bias3, x, (float*)d_out);
}

// Round 8
// 655.483 us; speedup vs baseline: 1.0416x; 1.0379x over previous
//
#include <hip/hip_runtime.h>
#include <hip/hip_bf16.h>
#include <cstdint>
#include <cstddef>

#define EPS_BN 1e-5f
#define LDK1 40         // LDS leading-dim stride (ushorts) for reg-staged conv1/conv3
#define TILE1 (128 * LDK1)

typedef __attribute__((ext_vector_type(8))) __bf16 bf16x8;
typedef __attribute__((ext_vector_type(4))) float f32x4;

__device__ __forceinline__ unsigned short f2b(float f) {
    __hip_bfloat16 h = __float2bfloat16(f);
    return __builtin_bit_cast(unsigned short, h);
}
__device__ __forceinline__ unsigned int pack2(float a, float b) {
    return (unsigned int)f2b(a) | ((unsigned int)f2b(b) << 16);
}
// wait lgkmcnt(0) only (vmcnt=63, expcnt=7 untouched), then raw barrier
__device__ __forceinline__ void lgkm_barrier() {
    __builtin_amdgcn_s_waitcnt(0xC07F);
    __builtin_amdgcn_s_barrier();
}
// counted vmcnt wait (lgkm=63 untouched) + barrier. N must be a literal <= 15.
#define VM_BARRIER(N) do { \
        __builtin_amdgcn_s_waitcnt(0x3F70 | (N)); \
        __builtin_amdgcn_s_barrier(); \
    } while (0)
// async global->LDS DMA, 16B per lane: writes lds_base + lane*16
__device__ __forceinline__ void load_lds16(const unsigned short* g, unsigned short* l) {
    __builtin_amdgcn_global_load_lds(
        (__attribute__((address_space(1))) void*)g,
        (__attribute__((address_space(3))) void*)l, 16, 0, 0);
}

// ---------------- prep kernels ----------------

__global__ void prep_bn_kernel(const float* __restrict__ g1, const float* __restrict__ b1,
                               const float* __restrict__ m1, const float* __restrict__ v1,
                               const float* __restrict__ g2, const float* __restrict__ b2,
                               const float* __restrict__ m2, const float* __restrict__ v2,
                               const float* __restrict__ g3, const float* __restrict__ b3,
                               const float* __restrict__ m3, const float* __restrict__ v3,
                               float* __restrict__ bias1, float* __restrict__ bias2,
                               float* __restrict__ bias3) {
    int t = blockIdx.x * 256 + threadIdx.x;
    if (t < 256) {
        float inv = g1[t] * rsqrtf(v1[t] + EPS_BN);
        bias1[t] = b1[t] - m1[t] * inv;
    } else if (t < 512) {
        int c = t - 256;
        float inv = g2[c] * rsqrtf(v2[c] + EPS_BN);
        bias2[c] = b2[c] - m2[c] * inv;
    } else if (t < 1536) {
        int c = t - 512;
        float inv = g3[c] * rsqrtf(v3[c] + EPS_BN);
        bias3[c] = b3[c] - m3[c] * inv;
    }
}

__global__ void repack_w1(const float* __restrict__ w1, const float* __restrict__ g1,
                          const float* __restrict__ v1, unsigned short* __restrict__ w1b) {
    int idx = blockIdx.x * 256 + threadIdx.x;  // < 262144
    int co = idx >> 10;
    float inv = g1[co] * rsqrtf(v1[co] + EPS_BN);
    w1b[idx] = f2b(w1[idx] * inv);
}

__global__ void repack_w2(const float* __restrict__ w2, const float* __restrict__ g2,
                          const float* __restrict__ v2, unsigned short* __restrict__ w2r) {
    int idx = blockIdx.x * 256 + threadIdx.x;  // < 589824
    int k9 = idx >> 16;
    int rem = idx & 65535;
    int co = rem >> 8;
    int ci = rem & 255;
    float inv = g2[co] * rsqrtf(v2[co] + EPS_BN);
    w2r[idx] = f2b(w2[(co * 256 + ci) * 9 + k9] * inv);
}

__global__ void repack_w3(const float* __restrict__ w3, const float* __restrict__ g3,
                          const float* __restrict__ v3, unsigned short* __restrict__ w3b) {
    int idx = blockIdx.x * 256 + threadIdx.x;  // < 262144
    int co = idx >> 8;
    float inv = g3[co] * rsqrtf(v3[co] + EPS_BN);
    w3b[idx] = f2b(w3[idx] * inv);
}

// zero only the halo cells of in2p (116 cells/image * 256 ch)
__global__ void halo_zero(unsigned short* __restrict__ in2p) {
    int idx = blockIdx.x * 256 + threadIdx.x;  // 928*256 = 64*116*32
    int cell = idx >> 5, l8 = idx & 31;
    int n = cell / 116, c = cell % 116;
    int h, w;
    if (c < 30)      { h = 0;      w = c; }
    else if (c < 60) { h = 29;     w = c - 30; }
    else if (c < 88) { h = c - 59; w = 0; }
    else             { h = c - 87; w = 29; }
    uint4 z = {0u, 0u, 0u, 0u};
    *reinterpret_cast<uint4*>(in2p + (((size_t)n * 900) + h * 30 + w) * 256 + l8 * 8) = z;
}

// ---------------- transpose: x (N,1024,784) fp32 -> xt (N,784,1024) bf16 ----------------
__global__ __launch_bounds__(256) void transpose_x(const float* __restrict__ x,
                                                   unsigned short* __restrict__ xt) {
    __shared__ float t[64][65];
    const int tid = threadIdx.x;
    const int sp0 = blockIdx.x * 64;
    const int c0 = blockIdx.y * 64;
    const int n = blockIdx.z;
    const float* xn = x + (size_t)n * 1024 * 784;

#pragma unroll
    for (int it = 0; it < 4; ++it) {
        int ci = it * 16 + (tid >> 4);
        int spl = (tid & 15) * 4;
        int sp = sp0 + spl;
        float4 v = {0.f, 0.f, 0.f, 0.f};
        if (sp < 784) v = *reinterpret_cast<const float4*>(xn + (size_t)(c0 + ci) * 784 + sp);
        t[ci][spl + 0] = v.x;
        t[ci][spl + 1] = v.y;
        t[ci][spl + 2] = v.z;
        t[ci][spl + 3] = v.w;
    }
    __syncthreads();

    unsigned short* xtn = xt + (size_t)n * 784 * 1024;
#pragma unroll
    for (int it = 0; it < 2; ++it) {
        int spl = it * 32 + (tid >> 3);
        int sp = sp0 + spl;
        if (sp >= 784) continue;
        int ci8 = (tid & 7) * 8;
        float v0 = t[ci8 + 0][spl], v1 = t[ci8 + 1][spl];
        float v2 = t[ci8 + 2][spl], v3 = t[ci8 + 3][spl];
        float v4 = t[ci8 + 4][spl], v5 = t[ci8 + 5][spl];
        float v6 = t[ci8 + 6][spl], v7 = t[ci8 + 7][spl];
        uint4 o = {pack2(v0, v1), pack2(v2, v3), pack2(v4, v5), pack2(v6, v7)};
        *reinterpret_cast<uint4*>(xtn + (size_t)sp * 1024 + c0 + ci8) = o;
    }
}

// ---------------- MFMA inner step (ld = LDS leading-dim stride, literal at call site) -----
// As[m][k] stride ld (m = A-tile row), Bs[n][k] stride ld (n = B-tile row).
// D: row(quad*4+reg) follows A, col(lane&15) follows B.
__device__ __forceinline__ void mfma_step(const unsigned short* As, const unsigned short* Bs,
                                          int aoff, int boff, int ld, f32x4 acc[4][4]) {
    bf16x8 a[4], b[4];
#pragma unroll
    for (int i = 0; i < 4; ++i)
        a[i] = *reinterpret_cast<const bf16x8*>(As + aoff + i * 16 * ld);
#pragma unroll
    for (int j = 0; j < 4; ++j)
        b[j] = *reinterpret_cast<const bf16x8*>(Bs + boff + j * 16 * ld);
#pragma unroll
    for (int i = 0; i < 4; ++i)
#pragma unroll
        for (int j = 0; j < 4; ++j)
            acc[i][j] = __builtin_amdgcn_mfma_f32_16x16x32_bf16(a[i], b[j], acc[i][j], 0, 0, 0);
}

// ---------------- conv1: 1x1 1024->256 GEMM, 2-deep reg prefetch; out NHWC bf16 + halo ----
// grid (392 flat-sp tiles, 2 co tiles), 256 threads
__global__ __launch_bounds__(256) void conv1_kernel(const unsigned short* __restrict__ xt,
                                                    const unsigned short* __restrict__ w1b,
                                                    const float* __restrict__ bias1,
                                                    unsigned short* __restrict__ in2p) {
    __shared__ unsigned short As[2][TILE1];
    __shared__ unsigned short Bs[2][TILE1];
    const int tid = threadIdx.x;
    const int f0 = blockIdx.x * 128;
    const int m0 = blockIdx.y * 128;
    const int lane = tid & 63, wave = tid >> 6;
    const int wr = wave >> 1, wc = wave & 1;
    const int l15 = lane & 15, quad = lane >> 4;
    const int tcid = tid & 3, tcl = tid >> 2;

    const unsigned short* aptr = w1b + (size_t)(m0 + tcl) * 1024 + tcid * 8;
    const unsigned short* bptr = xt + (size_t)(f0 + tcl) * 1024 + tcid * 8;

    f32x4 acc[4][4] = {};
    const int aoff = (wr * 64 + l15) * LDK1 + quad * 8;
    const int boff = (wc * 64 + l15) * LDK1 + quad * 8;
    const int wo = tcl * LDK1 + tcid * 8;

    // 2-deep register prefetch: slot0 = even k-steps, slot1 = odd
    uint4 a0s0, a1s0, b0s0, b1s0, a0s1, a1s1, b0s1, b1s1;
    a0s0 = *reinterpret_cast<const uint4*>(aptr);
    a1s0 = *reinterpret_cast<const uint4*>(aptr + 65536);
    b0s0 = *reinterpret_cast<const uint4*>(bptr);
    b1s0 = *reinterpret_cast<const uint4*>(bptr + 65536);
    a0s1 = *reinterpret_cast<const uint4*>(aptr + 32);
    a1s1 = *reinterpret_cast<const uint4*>(aptr + 65536 + 32);
    b0s1 = *reinterpret_cast<const uint4*>(bptr + 32);
    b1s1 = *reinterpret_cast<const uint4*>(bptr + 65536 + 32);

    for (int kk = 0; kk < 32; kk += 2) {
        {   // even step: slot0, LDS buf 0
            unsigned short* A = As[0];
            unsigned short* B = Bs[0];
            *reinterpret_cast<uint4*>(A + wo) = a0s0;
            *reinterpret_cast<uint4*>(A + 64 * LDK1 + wo) = a1s0;
            *reinterpret_cast<uint4*>(B + wo) = b0s0;
            *reinterpret_cast<uint4*>(B + 64 * LDK1 + wo) = b1s0;
            if (kk < 30) {
                int k0 = (kk + 2) * 32;
                a0s0 = *reinterpret_cast<const uint4*>(aptr + k0);
                a1s0 = *reinterpret_cast<const uint4*>(aptr + 65536 + k0);
                b0s0 = *reinterpret_cast<const uint4*>(bptr + k0);
                b1s0 = *reinterpret_cast<const uint4*>(bptr + 65536 + k0);
            }
            lgkm_barrier();
            mfma_step(A, B, aoff, boff, LDK1, acc);
        }
        {   // odd step: slot1, LDS buf 1
            unsigned short* A = As[1];
            unsigned short* B = Bs[1];
            *reinterpret_cast<uint4*>(A + wo) = a0s1;
            *reinterpret_cast<uint4*>(A + 64 * LDK1 + wo) = a1s1;
            *reinterpret_cast<uint4*>(B + wo) = b0s1;
            *reinterpret_cast<uint4*>(B + 64 * LDK1 + wo) = b1s1;
            if (kk < 30) {
                int k0 = (kk + 3) * 32;
                a0s1 = *reinterpret_cast<const uint4*>(aptr + k0);
                a1s1 = *reinterpret_cast<const uint4*>(aptr + 65536 + k0);
                b0s1 = *reinterpret_cast<const uint4*>(bptr + k0);
                b1s1 = *reinterpret_cast<const uint4*>(bptr + 65536 + k0);
            }
            lgkm_barrier();
            mfma_step(A, B, aoff, boff, LDK1, acc);
        }
    }

    // epilogue: bias + relu -> bf16 NHWC with +1 halo offset
#pragma unroll
    for (int j = 0; j < 4; ++j) {
        int f = f0 + wc * 64 + j * 16 + l15;
        int n = f / 784;
        int r = f - n * 784;
        int oh = r / 28, ow = r - oh * 28;
        unsigned short* dst = in2p + ((size_t)n * 900 + (oh + 1) * 30 + (ow + 1)) * 256;
#pragma unroll
        for (int i = 0; i < 4; ++i) {
            int co = m0 + wr * 64 + i * 16 + quad * 4;
            float4 bia = *reinterpret_cast<const float4*>(bias1 + co);
            f32x4 v = acc[i][j];
            ushort4 o;
            o.x = f2b(fmaxf(v.x + bia.x, 0.f));
            o.y = f2b(fmaxf(v.y + bia.y, 0.f));
            o.z = f2b(fmaxf(v.z + bia.z, 0.f));
            o.w = f2b(fmaxf(v.w + bia.w, 0.f));
            *reinterpret_cast<ushort4*>(dst + co) = o;
        }
    }
}

// ---------------- conv2: 3x3 = 72 k-steps; DMA staging, 3-buf, counted vmcnt --------------
// T4 pattern: stage(k+2) issued at step k; s_waitcnt vmcnt(8) guarantees stage(k) landed
// while stage(k+1)/(k+2) stay in flight (never drain to 0 in the main loop).
// grid (392, 2), 256 threads. LDS 3*2*8KB = 48KB -> 3 blocks/CU.
__global__ __launch_bounds__(256) void conv2_kernel(const unsigned short* __restrict__ in2p,
                                                    const unsigned short* __restrict__ w2r,
                                                    const float* __restrict__ bias2,
                                                    unsigned short* __restrict__ in3) {
    __shared__ unsigned short As[3][4096];
    __shared__ unsigned short Bs[3][4096];
    const int tid = threadIdx.x;
    const int f0 = blockIdx.x * 128;
    const int m0 = blockIdx.y * 128;
    const int lane = tid & 63, wave = tid >> 6;
    const int wr = wave >> 1, wc = wave & 1;
    const int l15 = lane & 15, quad = lane >> 4;
    const int srow = wave * 16 + (lane >> 2);   // staged row (0..63 half-tile)
    const int scol8 = (lane & 3) * 8;           // staged col (ushorts)
    const int lso = wave * 512;                 // per-wave LDS ushort base

    // halo-center cell index for this thread's two staged B rows
    int cellr[2];
#pragma unroll
    for (int p = 0; p < 2; ++p) {
        int f = f0 + p * 64 + srow;
        int n = f / 784;
        int r = f - n * 784;
        int oh = r / 28, ow = r - oh * 28;
        cellr[p] = n * 900 + (oh + 1) * 30 + (ow + 1);
    }

    const unsigned short* wbase = w2r + (size_t)(m0 + srow) * 256 + scol8;

    f32x4 acc[4][4] = {};
    const int aoff = (wr * 64 + l15) * 32 + quad * 8;
    const int boff = (wc * 64 + l15) * 32 + quad * 8;

#define STAGE2(cur, kn) do { \
        int k9_ = (kn) >> 3, cb_ = (kn) & 7; \
        int kh_ = k9_ / 3, kw_ = k9_ - 3 * kh_; \
        int dd_ = (kh_ - 1) * 30 + (kw_ - 1); \
        const unsigned short* wa_ = wbase + (size_t)k9_ * 65536 + cb_ * 32; \
        load_lds16(wa_, &As[cur][lso]); \
        load_lds16(wa_ + 16384, &As[cur][lso + 2048]); \
        const unsigned short* bb_ = in2p + (size_t)cb_ * 32 + scol8; \
        load_lds16(bb_ + (size_t)(cellr[0] + dd_) * 256, &Bs[cur][lso]); \
        load_lds16(bb_ + (size_t)(cellr[1] + dd_) * 256, &Bs[cur][lso + 2048]); \
    } while (0)

    STAGE2(0, 0);
    STAGE2(1, 1);
    for (int kk = 0; kk < 72; ++kk) {
        int cur = kk % 3;
        if (kk < 70) {
            STAGE2((kk + 2) % 3, kk + 2);
            VM_BARRIER(8);          // stage(kk) done; stage(kk+1,kk+2) in flight
        } else if (kk == 70) {
            VM_BARRIER(4);          // stage(70) done; stage(71) in flight
        } else {
            VM_BARRIER(0);          // final drain
        }
        mfma_step(As[cur], Bs[cur], aoff, boff, 32, acc);
        __builtin_amdgcn_s_barrier();   // all reads of buf[cur] done before its re-stage
    }
#undef STAGE2

    // epilogue: bias + relu -> bf16, flat [f][256]
#pragma unroll
    for (int j = 0; j < 4; ++j) {
        int f = f0 + wc * 64 + j * 16 + l15;
        unsigned short* dst = in3 + (size_t)f * 256;
#pragma unroll
        for (int i = 0; i < 4; ++i) {
            int co = m0 + wr * 64 + i * 16 + quad * 4;
            float4 bia = *reinterpret_cast<const float4*>(bias2 + co);
            f32x4 v = acc[i][j];
            ushort4 o;
            o.x = f2b(fmaxf(v.x + bia.x, 0.f));
            o.y = f2b(fmaxf(v.y + bia.y, 0.f));
            o.z = f2b(fmaxf(v.z + bia.z, 0.f));
            o.w = f2b(fmaxf(v.w + bia.w, 0.f));
            *reinterpret_cast<ushort4*>(dst + co) = o;
        }
    }
}

// ---------------- conv3: 1x1 256->1024; residual folded into acc-init; fp32 out -----------
// R5 form (best measured, 125us): A = spatial, B = weights; acc init = x + bias3 (C-in);
// 1-deep reg staging keeps natural VGPR < 128 -> 4 waves/SIMD. grid (392, 8), 256 threads
__global__ __launch_bounds__(256) void conv3_kernel(const unsigned short* __restrict__ in3,
                                                    const unsigned short* __restrict__ w3b,
                                                    const float* __restrict__ bias3,
                                                    const float* __restrict__ x,
                                                    float* __restrict__ out) {
    __shared__ unsigned short As[2][TILE1];
    __shared__ unsigned short Bs[2][TILE1];
    const int tid = threadIdx.x;
    const int f0 = blockIdx.x * 128;
    const int m0 = blockIdx.y * 128;
    const int lane = tid & 63, wave = tid >> 6;
    const int wr = wave >> 1, wc = wave & 1;
    const int l15 = lane & 15, quad = lane >> 4;
    const int tcid = tid & 3, tcl = tid >> 2;

    const unsigned short* aptr = in3 + (size_t)(f0 + tcl) * 256 + tcid * 8;   // spatial -> As
    const unsigned short* bptr = w3b + (size_t)(m0 + tcl) * 256 + tcid * 8;   // weights -> Bs

    const int aoff = (wr * 64 + l15) * LDK1 + quad * 8;
    const int boff = (wc * 64 + l15) * LDK1 + quad * 8;
    const int wo = tcl * LDK1 + tcid * 8;

    // staging prologue (1-deep)
    uint4 ra0, ra1, rb0, rb1;
    ra0 = *reinterpret_cast<const uint4*>(aptr);
    ra1 = *reinterpret_cast<const uint4*>(aptr + 16384);
    rb0 = *reinterpret_cast<const uint4*>(bptr);
    rb1 = *reinterpret_cast<const uint4*>(bptr + 16384);

    // accumulator init = residual + bias (MFMA C-in carries it through the k-loop)
    f32x4 acc[4][4];
#pragma unroll
    for (int j = 0; j < 4; ++j) {
        int co = m0 + wc * 64 + j * 16 + l15;
        float b = bias3[co];
#pragma unroll
        for (int i = 0; i < 4; ++i) {
            int fb = f0 + wr * 64 + i * 16 + quad * 4;
            int n = fb / 784;
            int sp = fb - n * 784;
            float4 xr = *reinterpret_cast<const float4*>(x + ((size_t)n * 1024 + co) * 784 + sp);
            f32x4 a;
            a.x = xr.x + b;
            a.y = xr.y + b;
            a.z = xr.z + b;
            a.w = xr.w + b;
            acc[i][j] = a;
        }
    }

    for (int kk = 0; kk < 8; ++kk) {
        unsigned short* A = As[kk & 1];
        unsigned short* B = Bs[kk & 1];
        *reinterpret_cast<uint4*>(A + wo) = ra0;
        *reinterpret_cast<uint4*>(A + 64 * LDK1 + wo) = ra1;
        *reinterpret_cast<uint4*>(B + wo) = rb0;
        *reinterpret_cast<uint4*>(B + 64 * LDK1 + wo) = rb1;
        if (kk < 7) {
            int k0 = (kk + 1) * 32;
            ra0 = *reinterpret_cast<const uint4*>(aptr + k0);
            ra1 = *reinterpret_cast<const uint4*>(aptr + 16384 + k0);
            rb0 = *reinterpret_cast<const uint4*>(bptr + k0);
            rb1 = *reinterpret_cast<const uint4*>(bptr + 16384 + k0);
        }
        lgkm_barrier();
        mfma_step(A, B, aoff, boff, LDK1, acc);
    }

    // epilogue: pure relu + float4 store (residual+bias already inside acc)
#pragma unroll
    for (int j = 0; j < 4; ++j) {
        int co = m0 + wc * 64 + j * 16 + l15;
#pragma unroll
        for (int i = 0; i < 4; ++i) {
            int fb = f0 + wr * 64 + i * 16 + quad * 4;
            int n = fb / 784;
            int sp = fb - n * 784;
            size_t off = ((size_t)n * 1024 + co) * 784 + sp;
            f32x4 v = acc[i][j];
            float4 o;
            o.x = fmaxf(v.x, 0.f);
            o.y = fmaxf(v.y, 0.f);
            o.z = fmaxf(v.z, 0.f);
            o.w = fmaxf(v.w, 0.f);
            *reinterpret_cast<float4*>(out + off) = o;
        }
    }
}

// ---------------- launch ----------------

extern "C" void kernel_launch(void* const* d_in, const int* in_sizes, int n_in,
                              void* d_out, int out_size, void* d_ws, size_t ws_size,
                              hipStream_t stream) {
    const float* x  = (const float*)d_in[0];
    const float* w1 = (const float*)d_in[1];
    const float* w2 = (const float*)d_in[2];
    const float* w3 = (const float*)d_in[3];
    const float* g1 = (const float*)d_in[4];
    const float* b1 = (const float*)d_in[5];
    const float* m1 = (const float*)d_in[6];
    const float* v1 = (const float*)d_in[7];
    const float* g2 = (const float*)d_in[8];
    const float* b2 = (const float*)d_in[9];
    const float* m2 = (const float*)d_in[10];
    const float* v2 = (const float*)d_in[11];
    const float* g3 = (const float*)d_in[12];
    const float* b3 = (const float*)d_in[13];
    const float* m3 = (const float*)d_in[14];
    const float* v3 = (const float*)d_in[15];

    char* ws = (char*)d_ws;
    unsigned short* w1b  = (unsigned short*)(ws + 0);         //   524288 B
    unsigned short* w2r  = (unsigned short*)(ws + 524288);    //  1179648 B
    unsigned short* w3b  = (unsigned short*)(ws + 1703936);   //   524288 B
    float* bias1         = (float*)(ws + 2228224);            //     1024 B
    float* bias2         = (float*)(ws + 2229248);            //     1024 B
    float* bias3         = (float*)(ws + 2230272);            //     4096 B
    unsigned short* in2p = (unsigned short*)(ws + 2234368);   // 29491200 B (64*900*256 bf16)
    unsigned short* xt   = (unsigned short*)(ws + 31725568);  // 102760448 B (64*784*1024 bf16)
    unsigned short* in3  = xt;  // aliases xt: xt is dead once conv1 finishes
    // total: 134486016 B (~134.5 MB)

    prep_bn_kernel<<<6, 256, 0, stream>>>(g1, b1, m1, v1, g2, b2, m2, v2, g3, b3, m3, v3,
                                          bias1, bias2, bias3);
    repack_w1<<<1024, 256, 0, stream>>>(w1, g1, v1, w1b);
    repack_w2<<<2304, 256, 0, stream>>>(w2, g2, v2, w2r);
    repack_w3<<<1024, 256, 0, stream>>>(w3, g3, v3, w3b);
    halo_zero<<<928, 256, 0, stream>>>(in2p);

    transpose_x<<<dim3(13, 16, 64), 256, 0, stream>>>(x, xt);
    conv1_kernel<<<dim3(392, 2), 256, 0, stream>>>(xt, w1b, bias1, in2p);
    conv2_kernel<<<dim3(392, 2), 256, 0, stream>>>(in2p, w2r, bias2, in3);
    conv3_kernel<<<dim3(392, 8), 256, 0, stream>>>(in3, w3b, bias3, x, (float*)d_out);
}

// Round 10
// 591.711 us; speedup vs baseline: 1.1539x; 1.1078x over previous
//
#include <hip/hip_runtime.h>
#include <hip/hip_bf16.h>
#include <cstdint>
#include <cstddef>

#define EPS_BN 1e-5f
#define LDK1 40         // LDS leading-dim stride (ushorts)
#define TILE1 (128 * LDK1)

typedef __attribute__((ext_vector_type(8))) __bf16 bf16x8;
typedef __attribute__((ext_vector_type(4))) float f32x4;

__device__ __forceinline__ unsigned short f2b(float f) {
    __hip_bfloat16 h = __float2bfloat16(f);
    return __builtin_bit_cast(unsigned short, h);
}
__device__ __forceinline__ unsigned int pack2(float a, float b) {
    return (unsigned int)f2b(a) | ((unsigned int)f2b(b) << 16);
}
// wait lgkmcnt(0) only (vmcnt=63, expcnt=7 untouched), then raw barrier
__device__ __forceinline__ void lgkm_barrier() {
    __builtin_amdgcn_s_waitcnt(0xC07F);
    __builtin_amdgcn_s_barrier();
}

// ---------------- prep kernels ----------------

__global__ void prep_bn_kernel(const float* __restrict__ g1, const float* __restrict__ b1,
                               const float* __restrict__ m1, const float* __restrict__ v1,
                               const float* __restrict__ g2, const float* __restrict__ b2,
                               const float* __restrict__ m2, const float* __restrict__ v2,
                               const float* __restrict__ g3, const float* __restrict__ b3,
                               const float* __restrict__ m3, const float* __restrict__ v3,
                               float* __restrict__ bias1, float* __restrict__ bias2,
                               float* __restrict__ bias3) {
    int t = blockIdx.x * 256 + threadIdx.x;
    if (t < 256) {
        float inv = g1[t] * rsqrtf(v1[t] + EPS_BN);
        bias1[t] = b1[t] - m1[t] * inv;
    } else if (t < 512) {
        int c = t - 256;
        float inv = g2[c] * rsqrtf(v2[c] + EPS_BN);
        bias2[c] = b2[c] - m2[c] * inv;
    } else if (t < 1536) {
        int c = t - 512;
        float inv = g3[c] * rsqrtf(v3[c] + EPS_BN);
        bias3[c] = b3[c] - m3[c] * inv;
    }
}

__global__ void repack_w1(const float* __restrict__ w1, const float* __restrict__ g1,
                          const float* __restrict__ v1, unsigned short* __restrict__ w1b) {
    int idx = blockIdx.x * 256 + threadIdx.x;  // < 262144
    int co = idx >> 10;
    float inv = g1[co] * rsqrtf(v1[co] + EPS_BN);
    w1b[idx] = f2b(w1[idx] * inv);
}

__global__ void repack_w2(const float* __restrict__ w2, const float* __restrict__ g2,
                          const float* __restrict__ v2, unsigned short* __restrict__ w2r) {
    int idx = blockIdx.x * 256 + threadIdx.x;  // < 589824
    int k9 = idx >> 16;
    int rem = idx & 65535;
    int co = rem >> 8;
    int ci = rem & 255;
    float inv = g2[co] * rsqrtf(v2[co] + EPS_BN);
    w2r[idx] = f2b(w2[(co * 256 + ci) * 9 + k9] * inv);
}

__global__ void repack_w3(const float* __restrict__ w3, const float* __restrict__ g3,
                          const float* __restrict__ v3, unsigned short* __restrict__ w3b) {
    int idx = blockIdx.x * 256 + threadIdx.x;  // < 262144
    int co = idx >> 8;
    float inv = g3[co] * rsqrtf(v3[co] + EPS_BN);
    w3b[idx] = f2b(w3[idx] * inv);
}

// zero only the halo cells of in2p (116 cells/image * 256 ch)
__global__ void halo_zero(unsigned short* __restrict__ in2p) {
    int idx = blockIdx.x * 256 + threadIdx.x;  // 928*256 = 64*116*32
    int cell = idx >> 5, l8 = idx & 31;
    int n = cell / 116, c = cell % 116;
    int h, w;
    if (c < 30)      { h = 0;      w = c; }
    else if (c < 60) { h = 29;     w = c - 30; }
    else if (c < 88) { h = c - 59; w = 0; }
    else             { h = c - 87; w = 29; }
    uint4 z = {0u, 0u, 0u, 0u};
    *reinterpret_cast<uint4*>(in2p + (((size_t)n * 900) + h * 30 + w) * 256 + l8 * 8) = z;
}

// ---------------- MFMA inner step (ld = LDS leading-dim stride) ----------------
// As[m][k] stride ld (m = A-tile row), Bs[n][k] stride ld (n = B-tile row).
// D: row(quad*4+reg) follows A, col(lane&15) follows B.
__device__ __forceinline__ void mfma_step(const unsigned short* As, const unsigned short* Bs,
                                          int aoff, int boff, int ld, f32x4 acc[4][4]) {
    bf16x8 a[4], b[4];
#pragma unroll
    for (int i = 0; i < 4; ++i)
        a[i] = *reinterpret_cast<const bf16x8*>(As + aoff + i * 16 * ld);
#pragma unroll
    for (int j = 0; j < 4; ++j)
        b[j] = *reinterpret_cast<const bf16x8*>(Bs + boff + j * 16 * ld);
#pragma unroll
    for (int i = 0; i < 4; ++i)
#pragma unroll
        for (int j = 0; j < 4; ++j)
            acc[i][j] = __builtin_amdgcn_mfma_f32_16x16x32_bf16(a[i], b[j], acc[i][j], 0, 0, 0);
}

// ---------------- conv1 (FUSED transpose): 1x1 1024->256, reads x NCHW directly ----------
// One block = 128 f x ALL 256 co (512 threads, 8 waves: wB=f-half, wA=co-quarter), so x is
// read exactly ONCE overall; xt workspace + transpose kernel eliminated (-309 MB traffic).
// B-staging does the transpose: per k-step each thread loads 8 x-floats (coalesced: 32
// lanes span 128 consecutive sp of one ci row) and writes 4 ds_write_b32 of pack2(ci,ci+1)
// into Bs[f][ci] (e-strided rows -> 4-way bank conflict, acceptable).
// A = weights (D rows = co), B = spatial (D cols = f). grid (392), 512 threads.
__global__ __launch_bounds__(512) void conv1_kernel(const float* __restrict__ x,
                                                    const unsigned short* __restrict__ w1b,
                                                    const float* __restrict__ bias1,
                                                    unsigned short* __restrict__ in2p) {
    __shared__ unsigned short As[2][256 * LDK1];   // 40960 B
    __shared__ unsigned short Bs[2][128 * LDK1];   // 20480 B
    const int tid = threadIdx.x;
    const int f0 = blockIdx.x * 128;
    const int lane = tid & 63, wave = tid >> 6;
    const int wA = wave & 3;     // co quarter
    const int wB = wave >> 2;    // f half
    const int l15 = lane & 15, quad = lane >> 4;

    // A staging: thread stages weight row ar, 16 ushorts at col half*16
    const int ar = tid >> 1, ah = (tid & 1) * 16;
    const unsigned short* aptr = w1b + (size_t)ar * 1024 + ah;
    const int awo = ar * LDK1 + ah;

    // B staging (transposed): cp = ci-pair (0..15), rows sq+32e (e=0..3)
    const int cp = tid >> 5, sq = tid & 31;
    const float* xb[4];
    int bwo[4];
#pragma unroll
    for (int e = 0; e < 4; ++e) {
        int f = f0 + sq + 32 * e;
        int n = f / 784, sp = f - n * 784;
        xb[e] = x + ((size_t)n * 1024 + 2 * cp) * 784 + sp;
        bwo[e] = (sq + 32 * e) * LDK1 + 2 * cp;
    }

    f32x4 acc[4][4] = {};
    const int aoff = (wA * 64 + l15) * LDK1 + quad * 8;
    const int boff = (wB * 64 + l15) * LDK1 + quad * 8;

    // 1-deep prefetch
    uint4 ra0, ra1;
    float bv0[4], bv1[4];
    ra0 = *reinterpret_cast<const uint4*>(aptr);
    ra1 = *reinterpret_cast<const uint4*>(aptr + 8);
#pragma unroll
    for (int e = 0; e < 4; ++e) { bv0[e] = xb[e][0]; bv1[e] = xb[e][784]; }

    for (int kk = 0; kk < 32; ++kk) {
        unsigned short* A = As[kk & 1];
        unsigned short* B = Bs[kk & 1];
        *reinterpret_cast<uint4*>(A + awo) = ra0;
        *reinterpret_cast<uint4*>(A + awo + 8) = ra1;
#pragma unroll
        for (int e = 0; e < 4; ++e)
            *reinterpret_cast<unsigned int*>(B + bwo[e]) = pack2(bv0[e], bv1[e]);
        if (kk < 31) {
            int ka = (kk + 1) * 32;
            ra0 = *reinterpret_cast<const uint4*>(aptr + ka);
            ra1 = *reinterpret_cast<const uint4*>(aptr + ka + 8);
            size_t kb = (size_t)(kk + 1) * 32 * 784;
#pragma unroll
            for (int e = 0; e < 4; ++e) { bv0[e] = xb[e][kb]; bv1[e] = xb[e][kb + 784]; }
        }
        lgkm_barrier();
        mfma_step(A, B, aoff, boff, LDK1, acc);
    }

    // epilogue: bias + relu -> bf16 NHWC with +1 halo offset
#pragma unroll
    for (int j = 0; j < 4; ++j) {
        int f = f0 + wB * 64 + j * 16 + l15;
        int n = f / 784;
        int r = f - n * 784;
        int oh = r / 28, ow = r - oh * 28;
        unsigned short* dst = in2p + ((size_t)n * 900 + (oh + 1) * 30 + (ow + 1)) * 256;
#pragma unroll
        for (int i = 0; i < 4; ++i) {
            int co = wA * 64 + i * 16 + quad * 4;
            float4 bia = *reinterpret_cast<const float4*>(bias1 + co);
            f32x4 v = acc[i][j];
            ushort4 o;
            o.x = f2b(fmaxf(v.x + bia.x, 0.f));
            o.y = f2b(fmaxf(v.y + bia.y, 0.f));
            o.z = f2b(fmaxf(v.z + bia.z, 0.f));
            o.w = f2b(fmaxf(v.w + bia.w, 0.f));
            *reinterpret_cast<ushort4*>(dst + co) = o;
        }
    }
}

// ---------------- conv2: 3x3 = 72 k-steps, 2-deep reg prefetch; out flat [f][256] bf16 ----
// grid (392, 2), 256 threads (R5 form — beat counted-DMA variant by ~9us in R5<->R8 A/B)
__global__ __launch_bounds__(256) void conv2_kernel(const unsigned short* __restrict__ in2p,
                                                    const unsigned short* __restrict__ w2r,
                                                    const float* __restrict__ bias2,
                                                    unsigned short* __restrict__ in3) {
    __shared__ unsigned short As[2][TILE1];
    __shared__ unsigned short Bs[2][TILE1];
    const int tid = threadIdx.x;
    const int f0 = blockIdx.x * 128;
    const int m0 = blockIdx.y * 128;
    const int lane = tid & 63, wave = tid >> 6;
    const int wr = wave >> 1, wc = wave & 1;
    const int l15 = lane & 15, quad = lane >> 4;
    const int tcid = tid & 3, tcl = tid >> 2;

    // per-thread halo-center cell index for its two B rows
    int cellc[2];
#pragma unroll
    for (int p = 0; p < 2; ++p) {
        int f = f0 + p * 64 + tcl;
        int n = f / 784;
        int r = f - n * 784;
        int oh = r / 28, ow = r - oh * 28;
        cellc[p] = n * 900 + (oh + 1) * 30 + (ow + 1);
    }

    f32x4 acc[4][4] = {};
    const int aoff = (wr * 64 + l15) * LDK1 + quad * 8;
    const int boff = (wc * 64 + l15) * LDK1 + quad * 8;
    const int wo = tcl * LDK1 + tcid * 8;

    uint4 a0s0, a1s0, b0s0, b1s0, a0s1, a1s1, b0s1, b1s1;
    {   // kn=0: k9=0, cb=0, dd=-31
        a0s0 = *reinterpret_cast<const uint4*>(w2r + (size_t)(m0 + tcl) * 256 + tcid * 8);
        a1s0 = *reinterpret_cast<const uint4*>(w2r + (size_t)(m0 + 64 + tcl) * 256 + tcid * 8);
        b0s0 = *reinterpret_cast<const uint4*>(in2p + (size_t)(cellc[0] - 31) * 256 + tcid * 8);
        b1s0 = *reinterpret_cast<const uint4*>(in2p + (size_t)(cellc[1] - 31) * 256 + tcid * 8);
    }
    {   // kn=1: k9=0, cb=1, dd=-31
        const unsigned short* wb = w2r + 32;
        a0s1 = *reinterpret_cast<const uint4*>(wb + (size_t)(m0 + tcl) * 256 + tcid * 8);
        a1s1 = *reinterpret_cast<const uint4*>(wb + (size_t)(m0 + 64 + tcl) * 256 + tcid * 8);
        const unsigned short* bb = in2p + 32 + tcid * 8;
        b0s1 = *reinterpret_cast<const uint4*>(bb + (size_t)(cellc[0] - 31) * 256);
        b1s1 = *reinterpret_cast<const uint4*>(bb + (size_t)(cellc[1] - 31) * 256);
    }

    for (int kk = 0; kk < 72; kk += 2) {
        {   // even step: slot0, LDS buf 0
            unsigned short* A = As[0];
            unsigned short* B = Bs[0];
            *reinterpret_cast<uint4*>(A + wo) = a0s0;
            *reinterpret_cast<uint4*>(A + 64 * LDK1 + wo) = a1s0;
            *reinterpret_cast<uint4*>(B + wo) = b0s0;
            *reinterpret_cast<uint4*>(B + 64 * LDK1 + wo) = b1s0;
            if (kk < 70) {
                int kn = kk + 2;
                int k9 = kn >> 3, cb = kn & 7;
                int kh = k9 / 3, kw = k9 - 3 * kh;
                int dd = (kh - 1) * 30 + (kw - 1);
                const unsigned short* wb = w2r + (size_t)k9 * 65536 + cb * 32;
                a0s0 = *reinterpret_cast<const uint4*>(wb + (size_t)(m0 + tcl) * 256 + tcid * 8);
                a1s0 = *reinterpret_cast<const uint4*>(wb + (size_t)(m0 + 64 + tcl) * 256 + tcid * 8);
                const unsigned short* bb = in2p + (size_t)cb * 32 + tcid * 8;
                b0s0 = *reinterpret_cast<const uint4*>(bb + (size_t)(cellc[0] + dd) * 256);
                b1s0 = *reinterpret_cast<const uint4*>(bb + (size_t)(cellc[1] + dd) * 256);
            }
            lgkm_barrier();
            mfma_step(A, B, aoff, boff, LDK1, acc);
        }
        {   // odd step: slot1, LDS buf 1
            unsigned short* A = As[1];
            unsigned short* B = Bs[1];
            *reinterpret_cast<uint4*>(A + wo) = a0s1;
            *reinterpret_cast<uint4*>(A + 64 * LDK1 + wo) = a1s1;
            *reinterpret_cast<uint4*>(B + wo) = b0s1;
            *reinterpret_cast<uint4*>(B + 64 * LDK1 + wo) = b1s1;
            if (kk < 70) {
                int kn = kk + 3;
                int k9 = kn >> 3, cb = kn & 7;
                int kh = k9 / 3, kw = k9 - 3 * kh;
                int dd = (kh - 1) * 30 + (kw - 1);
                const unsigned short* wb = w2r + (size_t)k9 * 65536 + cb * 32;
                a0s1 = *reinterpret_cast<const uint4*>(wb + (size_t)(m0 + tcl) * 256 + tcid * 8);
                a1s1 = *reinterpret_cast<const uint4*>(wb + (size_t)(m0 + 64 + tcl) * 256 + tcid * 8);
                const unsigned short* bb = in2p + (size_t)cb * 32 + tcid * 8;
                b0s1 = *reinterpret_cast<const uint4*>(bb + (size_t)(cellc[0] + dd) * 256);
                b1s1 = *reinterpret_cast<const uint4*>(bb + (size_t)(cellc[1] + dd) * 256);
            }
            lgkm_barrier();
            mfma_step(A, B, aoff, boff, LDK1, acc);
        }
    }

    // epilogue: bias + relu -> bf16, flat [f][256]
#pragma unroll
    for (int j = 0; j < 4; ++j) {
        int f = f0 + wc * 64 + j * 16 + l15;
        unsigned short* dst = in3 + (size_t)f * 256;
#pragma unroll
        for (int i = 0; i < 4; ++i) {
            int co = m0 + wr * 64 + i * 16 + quad * 4;
            float4 bia = *reinterpret_cast<const float4*>(bias2 + co);
            f32x4 v = acc[i][j];
            ushort4 o;
            o.x = f2b(fmaxf(v.x + bia.x, 0.f));
            o.y = f2b(fmaxf(v.y + bia.y, 0.f));
            o.z = f2b(fmaxf(v.z + bia.z, 0.f));
            o.w = f2b(fmaxf(v.w + bia.w, 0.f));
            *reinterpret_cast<ushort4*>(dst + co) = o;
        }
    }
}

// ---------------- conv3: 1x1 256->1024; residual folded into acc-init; fp32 out -----------
// R5 form (best measured): A = spatial, B = weights; acc init = x + bias3 (C-in);
// 1-deep reg staging keeps natural VGPR < 128 -> 4 waves/SIMD. grid (392, 8), 256 threads
__global__ __launch_bounds__(256) void conv3_kernel(const unsigned short* __restrict__ in3,
                                                    const unsigned short* __restrict__ w3b,
                                                    const float* __restrict__ bias3,
                                                    const float* __restrict__ x,
                                                    float* __restrict__ out) {
    __shared__ unsigned short As[2][TILE1];
    __shared__ unsigned short Bs[2][TILE1];
    const int tid = threadIdx.x;
    const int f0 = blockIdx.x * 128;
    const int m0 = blockIdx.y * 128;
    const int lane = tid & 63, wave = tid >> 6;
    const int wr = wave >> 1, wc = wave & 1;
    const int l15 = lane & 15, quad = lane >> 4;
    const int tcid = tid & 3, tcl = tid >> 2;

    const unsigned short* aptr = in3 + (size_t)(f0 + tcl) * 256 + tcid * 8;   // spatial -> As
    const unsigned short* bptr = w3b + (size_t)(m0 + tcl) * 256 + tcid * 8;   // weights -> Bs

    const int aoff = (wr * 64 + l15) * LDK1 + quad * 8;
    const int boff = (wc * 64 + l15) * LDK1 + quad * 8;
    const int wo = tcl * LDK1 + tcid * 8;

    // staging prologue (1-deep)
    uint4 ra0, ra1, rb0, rb1;
    ra0 = *reinterpret_cast<const uint4*>(aptr);
    ra1 = *reinterpret_cast<const uint4*>(aptr + 16384);
    rb0 = *reinterpret_cast<const uint4*>(bptr);
    rb1 = *reinterpret_cast<const uint4*>(bptr + 16384);

    // accumulator init = residual + bias (MFMA C-in carries it through the k-loop)
    f32x4 acc[4][4];
#pragma unroll
    for (int j = 0; j < 4; ++j) {
        int co = m0 + wc * 64 + j * 16 + l15;
        float b = bias3[co];
#pragma unroll
        for (int i = 0; i < 4; ++i) {
            int fb = f0 + wr * 64 + i * 16 + quad * 4;
            int n = fb / 784;
            int sp = fb - n * 784;
            float4 xr = *reinterpret_cast<const float4*>(x + ((size_t)n * 1024 + co) * 784 + sp);
            f32x4 a;
            a.x = xr.x + b;
            a.y = xr.y + b;
            a.z = xr.z + b;
            a.w = xr.w + b;
            acc[i][j] = a;
        }
    }

    for (int kk = 0; kk < 8; ++kk) {
        unsigned short* A = As[kk & 1];
        unsigned short* B = Bs[kk & 1];
        *reinterpret_cast<uint4*>(A + wo) = ra0;
        *reinterpret_cast<uint4*>(A + 64 * LDK1 + wo) = ra1;
        *reinterpret_cast<uint4*>(B + wo) = rb0;
        *reinterpret_cast<uint4*>(B + 64 * LDK1 + wo) = rb1;
        if (kk < 7) {
            int k0 = (kk + 1) * 32;
            ra0 = *reinterpret_cast<const uint4*>(aptr + k0);
            ra1 = *reinterpret_cast<const uint4*>(aptr + 16384 + k0);
            rb0 = *reinterpret_cast<const uint4*>(bptr + k0);
            rb1 = *reinterpret_cast<const uint4*>(bptr + 16384 + k0);
        }
        lgkm_barrier();
        mfma_step(A, B, aoff, boff, LDK1, acc);
    }

    // epilogue: pure relu + float4 store (residual+bias already inside acc)
#pragma unroll
    for (int j = 0; j < 4; ++j) {
        int co = m0 + wc * 64 + j * 16 + l15;
#pragma unroll
        for (int i = 0; i < 4; ++i) {
            int fb = f0 + wr * 64 + i * 16 + quad * 4;
            int n = fb / 784;
            int sp = fb - n * 784;
            size_t off = ((size_t)n * 1024 + co) * 784 + sp;
            f32x4 v = acc[i][j];
            float4 o;
            o.x = fmaxf(v.x, 0.f);
            o.y = fmaxf(v.y, 0.f);
            o.z = fmaxf(v.z, 0.f);
            o.w = fmaxf(v.w, 0.f);
            *reinterpret_cast<float4*>(out + off) = o;
        }
    }
}

// ---------------- launch ----------------

extern "C" void kernel_launch(void* const* d_in, const int* in_sizes, int n_in,
                              void* d_out, int out_size, void* d_ws, size_t ws_size,
                              hipStream_t stream) {
    const float* x  = (const float*)d_in[0];
    const float* w1 = (const float*)d_in[1];
    const float* w2 = (const float*)d_in[2];
    const float* w3 = (const float*)d_in[3];
    const float* g1 = (const float*)d_in[4];
    const float* b1 = (const float*)d_in[5];
    const float* m1 = (const float*)d_in[6];
    const float* v1 = (const float*)d_in[7];
    const float* g2 = (const float*)d_in[8];
    const float* b2 = (const float*)d_in[9];
    const float* m2 = (const float*)d_in[10];
    const float* v2 = (const float*)d_in[11];
    const float* g3 = (const float*)d_in[12];
    const float* b3 = (const float*)d_in[13];
    const float* m3 = (const float*)d_in[14];
    const float* v3 = (const float*)d_in[15];

    char* ws = (char*)d_ws;
    unsigned short* w1b  = (unsigned short*)(ws + 0);         //   524288 B
    unsigned short* w2r  = (unsigned short*)(ws + 524288);    //  1179648 B
    unsigned short* w3b  = (unsigned short*)(ws + 1703936);   //   524288 B
    float* bias1         = (float*)(ws + 2228224);            //     1024 B
    float* bias2         = (float*)(ws + 2229248);            //     1024 B
    float* bias3         = (float*)(ws + 2230272);            //     4096 B
    unsigned short* in2p = (unsigned short*)(ws + 2234368);   // 29491200 B (64*900*256 bf16)
    unsigned short* in3  = (unsigned short*)(ws + 31725568);  // 25690112 B (50176*256 bf16)
    // total: ~57.4 MB (xt eliminated)

    prep_bn_kernel<<<6, 256, 0, stream>>>(g1, b1, m1, v1, g2, b2, m2, v2, g3, b3, m3, v3,
                                          bias1, bias2, bias3);
    repack_w1<<<1024, 256, 0, stream>>>(w1, g1, v1, w1b);
    repack_w2<<<2304, 256, 0, stream>>>(w2, g2, v2, w2r);
    repack_w3<<<1024, 256, 0, stream>>>(w3, g3, v3, w3b);
    halo_zero<<<928, 256, 0, stream>>>(in2p);

    conv1_kernel<<<dim3(392), 512, 0, stream>>>(x, w1b, bias1, in2p);
    conv2_kernel<<<dim3(392, 2), 256, 0, stream>>>(in2p, w2r, bias2, in3);
    conv3_kernel<<<dim3(392, 8), 256, 0, stream>>>(in3, w3b, bias3, x, (float*)d_out);
}